// Round 6
// baseline (138.561 us; speedup 1.0000x reference)
//
#include <hip/hip_runtime.h>
#include <hip/hip_bf16.h>

// RGCN fused: per-relation aggregate (gather, fp32 acc) -> MFMA GEMM (K=8*64=512).
// x/linear fp32 on device, fp32 out (established r1-r3). Round 6:
//  - sched_barrier(0) after the 12-load batch: forces all 12 dwordx4 gather
//    loads in flight (r5's VGPR=52 proved the compiler re-serialized them).
//  - edge metas sorted by relation per node (64-thread sorting network at
//    staging) -> accumulate = running float4 + overwrite-flush to LDS.
//    ~13 VALU/edge instead of ~48 (8-way predicated FMA dispatch removed).
// W stays in d_ws as pre-packed bf16 B-fragments (L2-hot); LDS ~71 KB -> 2 blocks/CU.

#define THREADS 512
#define NPB 64            // nodes per block
#define KDIM 512          // NUM_REL * IN_CH
#define LDA 520           // padded bf16 row stride (1040 B)
#define MAXE 1024         // LDS edge-meta capacity (deg 12 -> 768 used)
#define WFRAG (4 * 16 * 64 * 8)   // 32768 bf16 B-fragment elements

typedef __attribute__((ext_vector_type(8))) short bf16x8;
typedef __attribute__((ext_vector_type(4))) float f32x4;

extern __shared__ __align__(16) char smem[];

__device__ __forceinline__ unsigned short f2bf(float f) {
  __hip_bfloat16 h = __float2bfloat16(f);
  return *reinterpret_cast<unsigned short*>(&h);
}

// ---- pack W (fp32 or bf16, [512][64]) -> bf16 B-fragment order in ws ----
__global__ __launch_bounds__(256) void pack_w(const void* __restrict__ wv,
                                              unsigned short* __restrict__ wsB) {
  const int lane = threadIdx.x & 63;
  const unsigned word = ((const unsigned*)wv)[lane];
  const int exf = (int)((word >> 7) & 0xFFu);
  const bool w_bf16 = __popcll(__ballot(exf >= 96 && exf < 160)) >= 48;
  for (int i = blockIdx.x * 256 + threadIdx.x; i < WFRAG; i += gridDim.x * 256) {
    const int j  = i & 7;
    const int l  = (i >> 3) & 63;
    const int kt = (i >> 9) & 15;
    const int nt = i >> 13;
    const int k  = kt * 32 + (l >> 4) * 8 + j;
    const int n  = nt * 16 + (l & 15);
    float v;
    if (w_bf16) v = __bfloat162float(((const __hip_bfloat16*)wv)[k * 64 + n]);
    else        v = ((const float*)wv)[k * 64 + n];
    wsB[i] = f2bf(v);
  }
}

#define ACC_SW(accrow, r, vv)                                        \
  switch (r) {                                                       \
    case 0: accrow[0] += (vv); break; case 1: accrow[1] += (vv); break; \
    case 2: accrow[2] += (vv); break; case 3: accrow[3] += (vv); break; \
    case 4: accrow[4] += (vv); break; case 5: accrow[5] += (vv); break; \
    case 6: accrow[6] += (vv); break; default: accrow[7] += (vv); break; }

__global__ __launch_bounds__(THREADS, 2)
void rgcn_fused(const void* __restrict__ xv,
                const void* __restrict__ wv,
                const int* __restrict__ p32,
                const int* __restrict__ i32,
                const int* __restrict__ t32,
                const unsigned short* __restrict__ wsB,  // null -> W staged in LDS
                float* __restrict__ out,
                int num_nodes) {
  __hip_bfloat16* aggS = (__hip_bfloat16*)smem;                 // [NPB][LDA]
  __hip_bfloat16* wtS  = aggS + NPB * LDA;                      // only if !wsB
  char* tail = smem + (size_t)NPB * LDA * 2 + (wsB ? 0 : (size_t)64 * LDA * 2);
  float*    invS  = (float*)tail;                               // [64]
  int*      ptrS  = (int*)(tail + 256);                         // [65]
  unsigned* eMeta = (unsigned*)(tail + 256 + 272);              // [MAXE]

  const int tid   = threadIdx.x;
  const int lane  = tid & 63;
  const int wvid  = tid >> 6;
  const int node0 = blockIdx.x * NPB;

  // runtime dtype / index-width detection (block-uniform)
  const unsigned xword = ((const unsigned*)xv)[lane];
  const int exf = (int)((xword >> 7) & 0xFFu);
  const bool x_bf16 = __popcll(__ballot(exf >= 96 && exf < 160)) >= 48;
  const bool idx64 = (p32[1] == 0);

  auto ldptr = [&](int n) -> int { return idx64 ? p32[2 * n] : p32[n]; };

  const int ntop   = min(node0 + NPB, num_nodes);
  const int e_lo   = ldptr(node0);
  const int ecount = ldptr(ntop) - e_lo;
  const bool staged = (ecount > 0 && ecount <= MAXE);

  for (int i = tid; i <= NPB; i += THREADS)
    ptrS[i] = ldptr(min(node0 + i, num_nodes));

  if (staged) {
    for (int e = tid; e < ecount; e += THREADS) {
      const int ge = e_lo + e;
      const unsigned s = (unsigned)(idx64 ? i32[2 * ge] : i32[ge]);
      const unsigned r = (unsigned)(idx64 ? t32[2 * ge] : t32[ge]);
      eMeta[e] = s | (r << 24);
    }
  }

  if (!wsB) {  // fallback: stage W^T in LDS (only if ws too small)
    if (x_bf16) {
      const __hip_bfloat16* wb = (const __hip_bfloat16*)wv;
      for (int i = tid; i < KDIM * 64; i += THREADS)
        wtS[(i & 63) * LDA + (i >> 6)] = wb[i];
    } else {
      const float* wf = (const float*)wv;
      for (int i = tid; i < KDIM * 64; i += THREADS)
        wtS[(i & 63) * LDA + (i >> 6)] = __float2bfloat16(wf[i]);
    }
  }

  __syncthreads();

  // inverse degree
  for (int i = tid; i < NPB; i += THREADS) {
    const int d = ptrS[i + 1] - ptrS[i];
    invS[i] = (d > 0 && node0 + i < num_nodes) ? 1.0f / (float)d : 0.0f;
  }

  // ---- sort each deg-12 node's metas by relation (top byte) ----
  // odd-even transposition network, branchless; thread tid handles node tid
  if (staged && tid < NPB) {
    const int e0 = ptrS[tid] - e_lo;
    if (ptrS[tid + 1] - ptrS[tid] == 12) {
      unsigned a[12];
#pragma unroll
      for (int j = 0; j < 12; ++j) a[j] = eMeta[e0 + j];
#pragma unroll
      for (int r = 0; r < 12; ++r)
#pragma unroll
        for (int i = (r & 1); i + 1 < 12; i += 2) {
          const unsigned lo = min(a[i], a[i + 1]);
          const unsigned hi = max(a[i], a[i + 1]);
          a[i] = lo; a[i + 1] = hi;
        }
#pragma unroll
      for (int j = 0; j < 12; ++j) eMeta[e0 + j] = a[j];
    }
  }

  __syncthreads();

  const int c16 = lane & 15;
  const int qd  = lane >> 4;

  // ---- gather: wave owns 8 nodes = 2 groups of 4; quad qd owns node nlb+qd ----
  auto gather = [&](auto xp, auto loadrow) {
#pragma unroll
    for (int g = 0; g < 2; ++g) {
      const int nlb = wvid * 8 + g * 4;
      const int eq0 = ptrS[nlb + qd] - e_lo;          // quad-uniform per lane
      const int dq  = ptrS[nlb + qd + 1] - e_lo - eq0;
      const bool okfast = staged && (node0 + nlb + 3 < num_nodes) &&
                          (__ballot(dq == 12) == ~0ull);
      if (okfast) {
        // metas (sorted by rel) from LDS
        unsigned m[12];
#pragma unroll
        for (int j = 0; j < 12; ++j) m[j] = eMeta[eq0 + j];
        // 12 independent dwordx4 loads; sched_barrier pins them all in flight
        float4 v[12];
#pragma unroll
        for (int j = 0; j < 12; ++j)
          v[j] = loadrow((int)(m[j] & 0x00FFFFFFu), c16);
        __builtin_amdgcn_sched_barrier(0);

        // zero-fill all 8 rel slots (overwritten below for present rels;
        // same-lane DS ops execute in order)
        unsigned short* dst0 =
            (unsigned short*)(aggS + (nlb + qd) * LDA) + 4 * c16;
        const ushort4 z4 = {0, 0, 0, 0};
#pragma unroll
        for (int r = 0; r < 8; ++r) *(ushort4*)(dst0 + r * 64) = z4;

        // sorted-run accumulate with overwrite-flush:
        // cur = cur*(same rel ? 1 : 0) + v;  write cur to rel's slot each edge
        float4 cur = make_float4(0.f, 0.f, 0.f, 0.f);
        unsigned prev = 0xFFFFFFFFu;
#pragma unroll
        for (int j = 0; j < 12; ++j) {
          const unsigned rj = m[j] >> 24;
          const float mk = (rj == prev) ? 1.0f : 0.0f;
          cur.x = fmaf(cur.x, mk, v[j].x);
          cur.y = fmaf(cur.y, mk, v[j].y);
          cur.z = fmaf(cur.z, mk, v[j].z);
          cur.w = fmaf(cur.w, mk, v[j].w);
          ushort4 b;
          b.x = f2bf(cur.x); b.y = f2bf(cur.y);
          b.z = f2bf(cur.z); b.w = f2bf(cur.w);
          *(ushort4*)(dst0 + rj * 64) = b;
          prev = rj;
        }
      } else {
        // generic: full wave per node, lane = channel, wave-uniform switch
#pragma unroll
        for (int t = 0; t < 4; ++t) {
          const int nl = nlb + t;
          float a[8] = {0.f, 0.f, 0.f, 0.f, 0.f, 0.f, 0.f, 0.f};
          if (node0 + nl < num_nodes) {
            const int e0 = ptrS[nl] - e_lo, e1 = ptrS[nl + 1] - e_lo;
            for (int e = e0; e < e1; ++e) {
              unsigned mm;
              if (staged) mm = eMeta[e];
              else {
                const int ge = e_lo + e;
                mm = (unsigned)(idx64 ? i32[2 * ge] : i32[ge]) |
                     ((unsigned)(idx64 ? t32[2 * ge] : t32[ge]) << 24);
              }
              const float vv = (float)xp[(size_t)(mm & 0x00FFFFFFu) * 64 + lane];
              const int r = __builtin_amdgcn_readfirstlane((int)(mm >> 24));
              ACC_SW(a, r, vv)
            }
          }
#pragma unroll
          for (int r = 0; r < 8; ++r)
            aggS[nl * LDA + r * 64 + lane] = __float2bfloat16(a[r]);
        }
      }
    }
  };

  if (x_bf16) {
    const __hip_bfloat16* xb = (const __hip_bfloat16*)xv;
    auto lr = [&](int src, int c) -> float4 {
      const ushort4 u = ((const ushort4*)xv)[src * 16 + c];
      float4 f;
      f.x = __uint_as_float((unsigned)(unsigned short)u.x << 16);
      f.y = __uint_as_float((unsigned)(unsigned short)u.y << 16);
      f.z = __uint_as_float((unsigned)(unsigned short)u.z << 16);
      f.w = __uint_as_float((unsigned)(unsigned short)u.w << 16);
      return f;
    };
    gather(xb, lr);
  } else {
    const float* xf = (const float*)xv;
    auto lr = [&](int src, int c) -> float4 {
      return ((const float4*)xv)[src * 16 + c];
    };
    gather(xf, lr);
  }

  __syncthreads();

  // ---- MFMA: out_tile[64x64] = agg[64x512] @ Wcat[512x64] ----
  const int mt  = wvid >> 1;
  const int nt0 = (wvid & 1) * 2;
  const int mi  = lane & 15;
  const int q4  = lane >> 4;
  const __hip_bfloat16* ap = aggS + (mt * 16 + mi) * LDA + q4 * 8;
  f32x4 c0 = {0.f, 0.f, 0.f, 0.f};
  f32x4 c1 = {0.f, 0.f, 0.f, 0.f};
  if (wsB) {
    const bf16x8* B = (const bf16x8*)wsB;
#pragma unroll
    for (int kt = 0; kt < KDIM / 32; ++kt) {
      const bf16x8 a  = *(const bf16x8*)(ap + kt * 32);
      const bf16x8 b0 = B[((nt0 + 0) * 16 + kt) * 64 + lane];
      const bf16x8 b1 = B[((nt0 + 1) * 16 + kt) * 64 + lane];
      c0 = __builtin_amdgcn_mfma_f32_16x16x32_bf16(a, b0, c0, 0, 0, 0);
      c1 = __builtin_amdgcn_mfma_f32_16x16x32_bf16(a, b1, c1, 0, 0, 0);
    }
  } else {
    const __hip_bfloat16* bp0 = wtS + ((nt0 + 0) * 16 + mi) * LDA + q4 * 8;
    const __hip_bfloat16* bp1 = wtS + ((nt0 + 1) * 16 + mi) * LDA + q4 * 8;
#pragma unroll
    for (int kt = 0; kt < KDIM / 32; ++kt) {
      const bf16x8 a  = *(const bf16x8*)(ap  + kt * 32);
      const bf16x8 b0 = *(const bf16x8*)(bp0 + kt * 32);
      const bf16x8 b1 = *(const bf16x8*)(bp1 + kt * 32);
      c0 = __builtin_amdgcn_mfma_f32_16x16x32_bf16(a, b0, c0, 0, 0, 0);
      c1 = __builtin_amdgcn_mfma_f32_16x16x32_bf16(a, b1, c1, 0, 0, 0);
    }
  }

  // D layout: col = lane&15, row = q4*4 + reg -> fp32 stores
#pragma unroll
  for (int i = 0; i < 4; ++i) {
    const int row  = q4 * 4 + i;
    const int nl   = mt * 16 + row;
    const int node = node0 + nl;
    if (node < num_nodes) {
      const float s = invS[nl];
      out[(size_t)node * 64 + (nt0 + 0) * 16 + mi] = c0[i] * s;
      out[(size_t)node * 64 + (nt0 + 1) * 16 + mi] = c1[i] * s;
    }
  }
}

extern "C" void kernel_launch(void* const* d_in, const int* in_sizes, int n_in,
                              void* d_out, int out_size, void* d_ws, size_t ws_size,
                              hipStream_t stream) {
  const void* x   = d_in[0];
  const void* w   = d_in[1];
  const int*  ptr = (const int*)d_in[2];
  const int*  idx = (const int*)d_in[3];
  const int*  et  = (const int*)d_in[4];
  float*      out = (float*)d_out;

  const int num_nodes = in_sizes[0] / 64;   // x is [N, 64]

  const bool useWs = (d_ws != nullptr) &&
                     (ws_size >= (size_t)WFRAG * sizeof(unsigned short));
  unsigned short* wsB = useWs ? (unsigned short*)d_ws : nullptr;
  if (useWs) pack_w<<<32, 256, 0, stream>>>(w, wsB);

  const size_t lds_bytes = (size_t)NPB * LDA * 2 +
                           (useWs ? 0 : (size_t)64 * LDA * 2) +
                           256 + 272 + (size_t)MAXE * 4;

  hipFuncSetAttribute((const void*)rgcn_fused,
                      hipFuncAttributeMaxDynamicSharedMemorySize,
                      (int)lds_bytes);

  const int nblocks = (num_nodes + NPB - 1) / NPB;
  rgcn_fused<<<nblocks, THREADS, lds_bytes, stream>>>(x, w, ptr, idx, et, wsB,
                                                      out, num_nodes);
}